// Round 1
// baseline (667.603 us; speedup 1.0000x reference)
//
#include <hip/hip_runtime.h>

#define E_TOT   300000
#define DN      128
#define DOUT    128

typedef float  f32x4  __attribute__((ext_vector_type(4)));
typedef __bf16 bf16x8 __attribute__((ext_vector_type(8)));
typedef unsigned int u32;

__device__ __forceinline__ unsigned short f2bf(float f) {
    union { float f; unsigned int u; } v; v.f = f;
    return (unsigned short)((v.u + 0x7FFFu + ((v.u >> 16) & 1u)) >> 16);
}

__device__ __forceinline__ u32 cvt_pk_bf16(float lo, float hi) {
    u32 r;
    asm("v_cvt_pk_bf16_f32 %0, %1, %2" : "=v"(r) : "v"(lo), "v"(hi));
    return r;
}

// 8 fp32 -> bf16x8 fragment (RNE, identical rounding to f2bf)
__device__ __forceinline__ bf16x8 make_frag(float4 u0, float4 u1) {
    union { u32 w[4]; bf16x8 v; } r;
    r.w[0] = cvt_pk_bf16(u0.x, u0.y);
    r.w[1] = cvt_pk_bf16(u0.z, u0.w);
    r.w[2] = cvt_pk_bf16(u1.x, u1.y);
    r.w[3] = cvt_pk_bf16(u1.z, u1.w);
    return r.v;
}

// Repack W1 [384][256] -> bf16 [6][256][64]  (chunk, n, k)  and
//        W2 [256][128] -> bf16 [4][128][64]
__global__ void prep_weights(const float* __restrict__ W1,
                             const float* __restrict__ W2,
                             unsigned short* __restrict__ W1p,
                             unsigned short* __restrict__ W2p) {
    int t = blockIdx.x * 256 + threadIdx.x;
    if (t < 384 * 256) {
        int k = t >> 8, n = t & 255;
        W1p[(((k >> 6) << 8) + n) * 64 + (k & 63)] = f2bf(W1[t]);
    } else {
        int t2 = t - 384 * 256;
        int k = t2 >> 7, n = t2 & 127;
        W2p[(((k >> 6) << 7) + n) * 64 + (k & 63)] = f2bf(W2[t2]);
    }
}

__global__ __launch_bounds__(256, 3) void edge_mlp(
    const float* __restrict__ node_attr,
    const float* __restrict__ edge_attr,
    const int*   __restrict__ eidx,
    const unsigned short* __restrict__ W1p,
    const unsigned short* __restrict__ W2p,
    const float* __restrict__ b1,
    const float* __restrict__ b2,
    const float* __restrict__ ln_g,
    const float* __restrict__ ln_b,
    float* __restrict__ out)
{
    // Only cross-wave exchange left: h matrix for layer 2. 33792 B -> LDS
    // no longer the occupancy limiter.
    __shared__ __align__(16) unsigned short hbuf[64 * 264];

    const int tid  = threadIdx.x;
    const int wid  = tid >> 6;
    const int lane = tid & 63;
    const int quad = lane >> 4;
    const int l16  = lane & 15;
    const int eb   = blockIdx.x * 64;

    // Per-lane byte offsets of the 4 m-tile rows this lane's A-fragments need.
    // (lane l16 holds row mt*16+l16; all 4 quads of an l16 share the row)
    u32 offS[4], offR[4], offE[4];
    #pragma unroll
    for (int mt = 0; mt < 4; ++mt) {
        int e = eb + (mt << 4) + l16;
        if (e >= E_TOT) e = E_TOT - 1;
        offS[mt] = (u32)eidx[e] * (DN * 4);
        offR[mt] = (u32)eidx[E_TOT + e] * (DN * 4);
        offE[mt] = (u32)e * (DN * 4);
    }

    f32x4 acc[4][4];
    #pragma unroll
    for (int i = 0; i < 4; ++i)
        #pragma unroll
        for (int j = 0; j < 4; ++j)
            acc[i][j] = (f32x4){0.f, 0.f, 0.f, 0.f};

    // ---------- Layer 1: X[64x384] @ W1[384x256], zero LDS, zero barriers ----
    // A-fragments: direct per-lane gather (fp32 -> cvt_pk bf16 in-register).
    // B-fragments: direct 16B loads from L2-resident W1p (n,k layout).
    const int fbase = ((0) << 6);  // placeholder to keep f0 arithmetic clear
    (void)fbase;
    #pragma unroll 1
    for (int c = 0; c < 6; ++c) {
        const int f0 = ((c & 1) << 6) + (quad << 3);  // float col: (c&1)*64 + quad*8
        bf16x8 a[2][4];                               // [ks][mt]
        #pragma unroll
        for (int mt = 0; mt < 4; ++mt) {
            u32 off = (c < 2) ? offS[mt] : (c < 4) ? offR[mt] : offE[mt];
            const char* basep = (const char*)((c < 4) ? node_attr : edge_attr);
            const float* s = (const float*)(basep + off);
            float4 u0 = *(const float4*)(s + f0);
            float4 u1 = *(const float4*)(s + f0 + 4);
            float4 v0 = *(const float4*)(s + f0 + 32);
            float4 v1 = *(const float4*)(s + f0 + 36);
            a[0][mt] = make_frag(u0, u1);
            a[1][mt] = make_frag(v0, v1);
        }
        const unsigned short* wbase = W1p + (((c << 8) + (wid << 6)) << 6);
        #pragma unroll
        for (int ks = 0; ks < 2; ++ks) {
            #pragma unroll
            for (int nt = 0; nt < 4; ++nt) {
                bf16x8 b = *(const bf16x8*)(wbase + (((nt << 4) + l16) << 6) + (ks << 5) + (quad << 3));
                #pragma unroll
                for (int mt = 0; mt < 4; ++mt)
                    acc[mt][nt] = __builtin_amdgcn_mfma_f32_16x16x32_bf16(a[ks][mt], b, acc[mt][nt], 0, 0, 0);
            }
        }
    }

    // bias + ReLU -> hbuf (the one cross-wave exchange)
    float b1v[4];
    #pragma unroll
    for (int nt = 0; nt < 4; ++nt) b1v[nt] = b1[(wid << 6) + (nt << 4) + l16];
    #pragma unroll
    for (int mt = 0; mt < 4; ++mt)
        #pragma unroll
        for (int nt = 0; nt < 4; ++nt)
            #pragma unroll
            for (int r = 0; r < 4; ++r) {
                int row = (mt << 4) + (quad << 2) + r;
                int col = (wid << 6) + (nt << 4) + l16;
                float v = acc[mt][nt][r] + b1v[nt];
                hbuf[row * 264 + col] = f2bf(v > 0.f ? v : 0.f);
            }
    __syncthreads();   // the only barrier in the kernel

    // ---------- Layer 2: h[64x256] @ W2[256x128] ----------
    // A from hbuf (conflict-free padded reads); B direct from L2-resident W2p.
    f32x4 acc2[8];
    #pragma unroll
    for (int nt = 0; nt < 8; ++nt) acc2[nt] = (f32x4){0.f, 0.f, 0.f, 0.f};

    #pragma unroll 1
    for (int c2 = 0; c2 < 4; ++c2) {
        const unsigned short* w2base = W2p + ((c2 << 7) << 6);
        #pragma unroll
        for (int ks = 0; ks < 2; ++ks) {
            bf16x8 a = *(const bf16x8*)(hbuf + ((wid << 4) + l16) * 264 + (c2 << 6) + (ks << 5) + (quad << 3));
            #pragma unroll
            for (int nt = 0; nt < 8; ++nt) {
                bf16x8 b = *(const bf16x8*)(w2base + (((nt << 4) + l16) << 6) + (ks << 5) + (quad << 3));
                acc2[nt] = __builtin_amdgcn_mfma_f32_16x16x32_bf16(a, b, acc2[nt], 0, 0, 0);
            }
        }
    }

    // ---------- bias + LayerNorm (in-register, 16-lane shuffle) ----------
    float b2v[8], gv[8], bev[8];
    #pragma unroll
    for (int nt = 0; nt < 8; ++nt) {
        int n = (nt << 4) + l16;
        b2v[nt] = b2[n]; gv[nt] = ln_g[n]; bev[nt] = ln_b[n];
    }
    #pragma unroll
    for (int r = 0; r < 4; ++r) {
        int e = eb + (wid << 4) + (quad << 2) + r;
        float x[8];
        float s = 0.f, s2 = 0.f;
        #pragma unroll
        for (int nt = 0; nt < 8; ++nt) {
            x[nt] = acc2[nt][r] + b2v[nt];
            s += x[nt]; s2 += x[nt] * x[nt];
        }
        #pragma unroll
        for (int m = 1; m < 16; m <<= 1) {
            s  += __shfl_xor(s, m, 64);
            s2 += __shfl_xor(s2, m, 64);
        }
        const float mu  = s * (1.f / 128.f);
        const float var = s2 * (1.f / 128.f) - mu * mu;
        const float rs  = rsqrtf(var + 1e-5f);
        if (e < E_TOT) {
            float* orow = out + (size_t)e * DOUT;
            #pragma unroll
            for (int nt = 0; nt < 8; ++nt)
                orow[(nt << 4) + l16] = (x[nt] - mu) * rs * gv[nt] + bev[nt];
        }
    }
}

extern "C" void kernel_launch(void* const* d_in, const int* in_sizes, int n_in,
                              void* d_out, int out_size, void* d_ws, size_t ws_size,
                              hipStream_t stream) {
    const float* node_attr = (const float*)d_in[0];
    const float* edge_attr = (const float*)d_in[1];
    const int*   eidx      = (const int*)d_in[2];
    const float* W1        = (const float*)d_in[3];
    const float* b1        = (const float*)d_in[4];
    const float* W2        = (const float*)d_in[5];
    const float* b2        = (const float*)d_in[6];
    const float* ln_g      = (const float*)d_in[7];
    const float* ln_b      = (const float*)d_in[8];

    unsigned short* W1p = (unsigned short*)d_ws;          // 98304 bf16
    unsigned short* W2p = W1p + 384 * 256;                // 32768 bf16

    prep_weights<<<512, 256, 0, stream>>>(W1, W2, W1p, W2p);

    const int nblocks = (E_TOT + 63) / 64;                // 4688
    edge_mlp<<<nblocks, 256, 0, stream>>>(node_attr, edge_attr, eidx,
                                          W1p, W2p, b1, b2, ln_g, ln_b,
                                          (float*)d_out);
}

// Round 2
// 536.772 us; speedup vs baseline: 1.2437x; 1.2437x over previous
//
#include <hip/hip_runtime.h>

#define E_TOT   300000
#define DN      128
#define DOUT    128

typedef float  f32x4  __attribute__((ext_vector_type(4)));
typedef __bf16 bf16x8 __attribute__((ext_vector_type(8)));
typedef unsigned int u32;

__device__ __forceinline__ unsigned short f2bf(float f) {
    union { float f; unsigned int u; } v; v.f = f;
    return (unsigned short)((v.u + 0x7FFFu + ((v.u >> 16) & 1u)) >> 16);
}

// Repack W1 [384][256] -> bf16 [6][256][64]  (chunk, n, k)  and
//        W2 [256][128] -> bf16 [4][128][64]
__global__ void prep_weights(const float* __restrict__ W1,
                             const float* __restrict__ W2,
                             unsigned short* __restrict__ W1p,
                             unsigned short* __restrict__ W2p) {
    int t = blockIdx.x * 256 + threadIdx.x;
    if (t < 384 * 256) {
        int k = t >> 8, n = t & 255;
        W1p[(((k >> 6) << 8) + n) * 64 + (k & 63)] = f2bf(W1[t]);
    } else {
        int t2 = t - 384 * 256;
        int k = t2 >> 7, n = t2 & 127;
        W2p[(((k >> 6) << 7) + n) * 64 + (k & 63)] = f2bf(W2[t2]);
    }
}

__global__ __launch_bounds__(256, 3) void edge_mlp(
    const float* __restrict__ node_attr,
    const float* __restrict__ edge_attr,
    const int*   __restrict__ eidx,
    const unsigned short* __restrict__ W1p,
    const unsigned short* __restrict__ W2p,
    const float* __restrict__ b1,
    const float* __restrict__ b2,
    const float* __restrict__ ln_g,
    const float* __restrict__ ln_b,
    float* __restrict__ out)
{
    // LDS: X double-buffer (gather staging only) + h exchange. W never
    // round-trips LDS: B-fragments come straight from L2-resident W1p/W2p
    // whose (n,k) layout makes every B-load 16 fully-used 64B lines.
    __shared__ __align__(16) unsigned short Xc[2][64 * 72];   // 18432 B
    __shared__ __align__(16) unsigned short hbuf[64 * 264];   // 33792 B

    const int tid  = threadIdx.x;
    const int wid  = tid >> 6;
    const int lane = tid & 63;
    const int quad = lane >> 4;
    const int l16  = lane & 15;
    const int eb   = blockIdx.x * 64;

    // Staging geometry: thread handles rows r0+16i (i=0..3), 16B at col q4.
    const int r0 = tid >> 4;
    const int q4 = tid & 15;

    // Per-thread gather byte-offsets (eidx read redundantly x16 lanes; L1 hit).
    u32 sOff[4], rOff[4], eOff[4];
    #pragma unroll
    for (int i = 0; i < 4; ++i) {
        int e = eb + r0 + (i << 4);
        if (e >= E_TOT) e = E_TOT - 1;
        sOff[i] = (u32)eidx[e] * (DN * 4);
        rOff[i] = (u32)eidx[E_TOT + e] * (DN * 4);
        eOff[i] = (u32)e * (DN * 4);
    }

    f32x4 acc[4][4];
    #pragma unroll
    for (int i = 0; i < 4; ++i)
        #pragma unroll
        for (int j = 0; j < 4; ++j)
            acc[i][j] = (f32x4){0.f, 0.f, 0.f, 0.f};

    // ---------- Layer 1: X[64x384] @ W1[384x256], 1 barrier/chunk ----------
    float4 pf[4];

    // prologue: gather chunk 0, write Xc[0]
    #pragma unroll
    for (int i = 0; i < 4; ++i)
        pf[i] = *(const float4*)((const char*)node_attr + sOff[i] + (q4 << 4));
    #pragma unroll
    for (int i = 0; i < 4; ++i) {
        ushort4 p;
        p.x = f2bf(pf[i].x); p.y = f2bf(pf[i].y);
        p.z = f2bf(pf[i].z); p.w = f2bf(pf[i].w);
        *(ushort4*)(&Xc[0][(r0 + (i << 4)) * 72 + (q4 << 2)]) = p;
    }

    #pragma unroll 1
    for (int c = 0; c < 6; ++c) {
        __syncthreads();                       // Xc[c&1] fully written

        // issue next chunk's gather immediately (latency hides under MFMA)
        if (c < 5) {
            const int cn = c + 1;
            const u32 coloff = ((cn & 1) << 8) + (q4 << 4);  // bytes
            #pragma unroll
            for (int i = 0; i < 4; ++i) {
                u32 off;
                const char* base;
                if (cn < 2)      { base = (const char*)node_attr; off = sOff[i]; }
                else if (cn < 4) { base = (const char*)node_attr; off = rOff[i]; }
                else             { base = (const char*)edge_attr; off = eOff[i]; }
                pf[i] = *(const float4*)(base + off + coloff);
            }
        }

        // hoist all 8 B-fragment loads for this chunk (L2, fully-used lines)
        const unsigned short* wbase = W1p + (((c << 8) + (wid << 6)) << 6);
        bf16x8 bfr[2][4];
        #pragma unroll
        for (int ks = 0; ks < 2; ++ks)
            #pragma unroll
            for (int nt = 0; nt < 4; ++nt)
                bfr[ks][nt] = *(const bf16x8*)(wbase + (((nt << 4) + l16) << 6) + (ks << 5) + (quad << 3));

        const unsigned short* X = &Xc[c & 1][0];
        #pragma unroll
        for (int ks = 0; ks < 2; ++ks) {
            bf16x8 a[4];
            #pragma unroll
            for (int mt = 0; mt < 4; ++mt)
                a[mt] = *(const bf16x8*)(X + ((mt << 4) + l16) * 72 + (ks << 5) + (quad << 3));
            #pragma unroll
            for (int nt = 0; nt < 4; ++nt)
                #pragma unroll
                for (int mt = 0; mt < 4; ++mt)
                    acc[mt][nt] = __builtin_amdgcn_mfma_f32_16x16x32_bf16(a[mt], bfr[ks][nt], acc[mt][nt], 0, 0, 0);
        }

        // write prefetched chunk into the other buffer (no reader until
        // after next barrier)
        if (c < 5) {
            unsigned short* Xn = &Xc[(c + 1) & 1][0];
            #pragma unroll
            for (int i = 0; i < 4; ++i) {
                ushort4 p;
                p.x = f2bf(pf[i].x); p.y = f2bf(pf[i].y);
                p.z = f2bf(pf[i].z); p.w = f2bf(pf[i].w);
                *(ushort4*)(Xn + (r0 + (i << 4)) * 72 + (q4 << 2)) = p;
            }
        }
    }

    // bias + ReLU -> hbuf (the one cross-wave exchange for layer 2)
    float b1v[4];
    #pragma unroll
    for (int nt = 0; nt < 4; ++nt) b1v[nt] = b1[(wid << 6) + (nt << 4) + l16];
    #pragma unroll
    for (int mt = 0; mt < 4; ++mt)
        #pragma unroll
        for (int nt = 0; nt < 4; ++nt)
            #pragma unroll
            for (int r = 0; r < 4; ++r) {
                int row = (mt << 4) + (quad << 2) + r;
                int col = (wid << 6) + (nt << 4) + l16;
                float v = acc[mt][nt][r] + b1v[nt];
                hbuf[row * 264 + col] = f2bf(v > 0.f ? v : 0.f);
            }
    __syncthreads();

    // ---------- Layer 2: h[64x256] @ W2[256x128], B direct from L2 ----------
    f32x4 acc2[8];
    #pragma unroll
    for (int nt = 0; nt < 8; ++nt) acc2[nt] = (f32x4){0.f, 0.f, 0.f, 0.f};

    #pragma unroll 1
    for (int c2 = 0; c2 < 4; ++c2) {
        const unsigned short* w2base = W2p + (c2 << 13);
        #pragma unroll
        for (int ks = 0; ks < 2; ++ks) {
            bf16x8 b2f[8];
            #pragma unroll
            for (int nt = 0; nt < 8; ++nt)
                b2f[nt] = *(const bf16x8*)(w2base + (((nt << 4) + l16) << 6) + (ks << 5) + (quad << 3));
            bf16x8 a = *(const bf16x8*)(hbuf + ((wid << 4) + l16) * 264 + (c2 << 6) + (ks << 5) + (quad << 3));
            #pragma unroll
            for (int nt = 0; nt < 8; ++nt)
                acc2[nt] = __builtin_amdgcn_mfma_f32_16x16x32_bf16(a, b2f[nt], acc2[nt], 0, 0, 0);
        }
    }

    // ---------- bias + LayerNorm (in-register, 16-lane shuffle) ----------
    float b2v[8], gv[8], bev[8];
    #pragma unroll
    for (int nt = 0; nt < 8; ++nt) {
        int n = (nt << 4) + l16;
        b2v[nt] = b2[n]; gv[nt] = ln_g[n]; bev[nt] = ln_b[n];
    }
    #pragma unroll
    for (int r = 0; r < 4; ++r) {
        int e = eb + (wid << 4) + (quad << 2) + r;
        float x[8];
        float s = 0.f, s2 = 0.f;
        #pragma unroll
        for (int nt = 0; nt < 8; ++nt) {
            x[nt] = acc2[nt][r] + b2v[nt];
            s += x[nt]; s2 += x[nt] * x[nt];
        }
        #pragma unroll
        for (int m = 1; m < 16; m <<= 1) {
            s  += __shfl_xor(s, m, 64);
            s2 += __shfl_xor(s2, m, 64);
        }
        const float mu  = s * (1.f / 128.f);
        const float var = s2 * (1.f / 128.f) - mu * mu;
        const float rs  = rsqrtf(var + 1e-5f);
        if (e < E_TOT) {
            float* orow = out + (size_t)e * DOUT;
            #pragma unroll
            for (int nt = 0; nt < 8; ++nt)
                orow[(nt << 4) + l16] = (x[nt] - mu) * rs * gv[nt] + bev[nt];
        }
    }
}

extern "C" void kernel_launch(void* const* d_in, const int* in_sizes, int n_in,
                              void* d_out, int out_size, void* d_ws, size_t ws_size,
                              hipStream_t stream) {
    const float* node_attr = (const float*)d_in[0];
    const float* edge_attr = (const float*)d_in[1];
    const int*   eidx      = (const int*)d_in[2];
    const float* W1        = (const float*)d_in[3];
    const float* b1        = (const float*)d_in[4];
    const float* W2        = (const float*)d_in[5];
    const float* b2        = (const float*)d_in[6];
    const float* ln_g      = (const float*)d_in[7];
    const float* ln_b      = (const float*)d_in[8];

    unsigned short* W1p = (unsigned short*)d_ws;          // 98304 bf16
    unsigned short* W2p = W1p + 384 * 256;                // 32768 bf16

    prep_weights<<<512, 256, 0, stream>>>(W1, W2, W1p, W2p);

    const int nblocks = (E_TOT + 63) / 64;                // 4688
    edge_mlp<<<nblocks, 256, 0, stream>>>(node_attr, edge_attr, eidx,
                                          W1p, W2p, b1, b2, ln_g, ln_b,
                                          (float*)d_out);
}